// Round 5
// baseline (11.764 us; speedup 1.0000x reference)
//
#include <hip/hip_runtime.h>

// Single-dispatch, single-block geo landmark loss via bf16 MFMA.
//   D[r][b] = sum_k R[r][k] * cd[k][b],  r<204 (pad 224), k<144 (pad 160), b<64
//   loss = sum_{r,b} w[r/3] * D[r][b]^2 / 68
// 7 waves x 2 M-tiles each: B fragments (identical across M-tiles) are read
// from LDS once per (s,t) and reused -> 140 ds_read_b128 instead of 260.
// No atomics, no workspace, no zero-init requirements -> graph-replay safe.

#define NUM_LM 68
#define K_ID 80
#define K_EXP 64
#define NROWS 204
#define NWAVES 7
#define MT 2                    // M-tiles per wave
#define BLOCK (NWAVES * 64)     // 448 threads
#define CD_STRIDE 168           // bf16 elems per batch row (padded from 160)

typedef short bf16x8 __attribute__((ext_vector_type(8)));
typedef float f32x4  __attribute__((ext_vector_type(4)));

__device__ __constant__ int LM_IDX[NUM_LM] = {
    27440, 27208, 27608, 27816, 35472, 34766, 34312, 34022, 33838, 33654,
    33375, 32939, 32244, 16264, 16467, 16888, 16644, 31716, 31056, 30662,
    30454, 30288, 29549, 29382, 29177, 28787, 28111,  8161,  8177,  8187,
     8192,  9883,  9163,  8204,  7243,  6515, 14066, 12383, 11353, 10455,
    11492, 12653,  5828,  4920,  3886,  2215,  3640,  4801, 10795, 10395,
     8935,  8215,  7495,  6025,  5522,  6915,  7636,  8236,  8836,  9555,
    10537,  9064,  8223,  7384,  5909,  7629,  8229,  8829
};

__device__ __forceinline__ unsigned short f2bf(float f) {
    union { float f; unsigned u; } v; v.f = f;
    unsigned r = v.u + 0x7FFFu + ((v.u >> 16) & 1u);   // round-nearest-even
    return (unsigned short)(r >> 16);
}

__global__ __launch_bounds__(BLOCK) void fused_geo_loss(
        const float* __restrict__ alpha,
        const float* __restrict__ delta,
        const float* __restrict__ ref_alpha,
        const float* __restrict__ delta_pred,
        const float* __restrict__ id_base,
        const float* __restrict__ exp_base,
        float* __restrict__ out) {
    __shared__ __align__(16) unsigned short cdT[64 * CD_STRIDE];
    __shared__ float red[NWAVES];

    const int tid = threadIdx.x;
    const int w   = tid >> 6;      // wave: owns M-tiles 2w, 2w+1
    const int l   = tid & 63;      // lane
    const int mh  = l & 15;        // row-hat within tile (A) / col-hat (B)
    const int g   = l >> 4;        // k-group

    // ---- A-operand gather (global -> VGPR), issued before LDS staging ----
    float4 af[MT][5][2];
    #pragma unroll
    for (int u = 0; u < MT; ++u) {
        const int  m     = 32 * w + 16 * u + mh;    // 0..223
        const bool valid = m < NROWS;
        const int  lmi   = valid ? (m / 3) : 0;
        const int  cc    = m - 3 * (m / 3);
        const long long vrow = 3LL * LM_IDX[lmi] + cc;
        const float* __restrict__ idp = id_base  + vrow * K_ID;
        const float* __restrict__ exq = exp_base + vrow * K_EXP;
        #pragma unroll
        for (int s = 0; s < 5; ++s) {
            const int k0 = 32 * s + g * 8;   // lane's 8-wide k-chunk, no straddle
            if (valid && k0 < K_ID) {
                af[u][s][0] = *(const float4*)(idp + k0);
                af[u][s][1] = *(const float4*)(idp + k0 + 4);
            } else if (valid && k0 < K_ID + K_EXP) {
                af[u][s][0] = *(const float4*)(exq + (k0 - K_ID));
                af[u][s][1] = *(const float4*)(exq + (k0 - K_ID) + 4);
            } else {
                af[u][s][0] = float4{0.f, 0.f, 0.f, 0.f};
                af[u][s][1] = float4{0.f, 0.f, 0.f, 0.f};
            }
        }
    }

    // ---- stage coeff diffs transposed into LDS as bf16: cdT[b][k] ----
    for (int i = tid; i < (64 * K_ID) / 4; i += BLOCK) {        // 1280 float4
        float4 a4 = ((const float4*)alpha)[i];
        float4 r4 = ((const float4*)ref_alpha)[i];
        const int e = i * 4, b = e / K_ID, k = e - b * K_ID;
        unsigned short* p = &cdT[b * CD_STRIDE + k];
        p[0] = f2bf(a4.x - r4.x); p[1] = f2bf(a4.y - r4.y);
        p[2] = f2bf(a4.z - r4.z); p[3] = f2bf(a4.w - r4.w);
    }
    for (int i = tid; i < (64 * K_EXP) / 4; i += BLOCK) {       // 1024 float4
        float4 d4 = ((const float4*)delta)[i];
        float4 q4 = ((const float4*)delta_pred)[i];
        const int e = i * 4, b = e >> 6, k = e & 63;
        unsigned short* p = &cdT[b * CD_STRIDE + K_ID + k];
        p[0] = f2bf(d4.x - q4.x); p[1] = f2bf(d4.y - q4.y);
        p[2] = f2bf(d4.z - q4.z); p[3] = f2bf(d4.w - q4.w);
    }
    for (int i = tid; i < 64 * 4; i += BLOCK) {                 // zero k=144..159
        const int b = i >> 2, k = 144 + 4 * (i & 3);
        *(ushort4*)&cdT[b * CD_STRIDE + k] = ushort4{0, 0, 0, 0};
    }

    // convert A fragments to bf16 while staging loads are in flight
    bf16x8 a[MT][5];
    #pragma unroll
    for (int u = 0; u < MT; ++u)
        #pragma unroll
        for (int s = 0; s < 5; ++s) {
            const float* fp = (const float*)&af[u][s][0];
            #pragma unroll
            for (int j = 0; j < 8; ++j) a[u][s][j] = (short)f2bf(fp[j]);
        }

    __syncthreads();

    // ---- MFMA: 5 k-steps x 4 N-tiles, B read once and reused for both M ----
    f32x4 acc[MT][4];
    const f32x4 z4 = {0.f, 0.f, 0.f, 0.f};
    #pragma unroll
    for (int u = 0; u < MT; ++u)
        #pragma unroll
        for (int t = 0; t < 4; ++t) acc[u][t] = z4;

    #pragma unroll
    for (int s = 0; s < 5; ++s) {
        bf16x8 bfrag[4];
        #pragma unroll
        for (int t = 0; t < 4; ++t)
            bfrag[t] = *(const bf16x8*)&cdT[(16 * t + mh) * CD_STRIDE + 32 * s + g * 8];
        #pragma unroll
        for (int u = 0; u < MT; ++u)
            #pragma unroll
            for (int t = 0; t < 4; ++t)
                acc[u][t] = __builtin_amdgcn_mfma_f32_16x16x32_bf16(
                    a[u][s], bfrag[t], acc[u][t], 0, 0, 0);
    }

    // ---- weighted square-sum; D layout: col=lane&15, row=(lane>>4)*4+reg ----
    float v = 0.f;
    #pragma unroll
    for (int u = 0; u < MT; ++u) {
        #pragma unroll
        for (int q = 0; q < 4; ++q) {
            const int row = 32 * w + 16 * u + 4 * g + q;
            float wq = 0.f;
            if (row < NROWS) {
                const int li = row / 3;
                wq = ((li >= 17 && li < 27) || li >= 36) ? 50.f : 1.f;
            }
            float sq = 0.f;
            #pragma unroll
            for (int t = 0; t < 4; ++t) sq += acc[u][t][q] * acc[u][t][q];
            v += wq * sq;
        }
    }
    #pragma unroll
    for (int off = 32; off; off >>= 1) v += __shfl_down(v, off, 64);
    if (l == 0) red[w] = v;
    __syncthreads();
    if (tid == 0) {
        float tot = 0.f;
        #pragma unroll
        for (int i = 0; i < NWAVES; ++i) tot += red[i];
        out[0] = tot * (1.0f / 68.0f);
    }
}

extern "C" void kernel_launch(void* const* d_in, const int* in_sizes, int n_in,
                              void* d_out, int out_size, void* d_ws, size_t ws_size,
                              hipStream_t stream) {
    const float* alpha      = (const float*)d_in[0];
    const float* delta      = (const float*)d_in[1];
    const float* ref_alpha  = (const float*)d_in[2];
    const float* delta_pred = (const float*)d_in[3];
    const float* id_base    = (const float*)d_in[4];
    const float* exp_base   = (const float*)d_in[5];
    float* out = (float*)d_out;

    fused_geo_loss<<<dim3(1), dim3(BLOCK), 0, stream>>>(
        alpha, delta, ref_alpha, delta_pred, id_base, exp_base, out);
}

// Round 6
// 11.595 us; speedup vs baseline: 1.0145x; 1.0145x over previous
//
#include <hip/hip_runtime.h>
#include <hip/hip_bf16.h>

// Single-dispatch, single-block geo landmark loss via bf16 MFMA.
//   D[r][b] = sum_k R[r][k] * cd[k][b],  r<204 (pad 224), k<144 (pad 160), b<64
//   loss = sum_{r,b} w[r/3] * D[r][b]^2 / 68
// 7 waves x 2 M-tiles. Staging uses packed v_cvt_pk_bf16_f32 (via
// __float22bfloat162_rn) and ds_write_b128 (8 bf16 per write).
// No atomics, no workspace, no zero-init requirements -> graph-replay safe.

#define NUM_LM 68
#define K_ID 80
#define K_EXP 64
#define NROWS 204
#define NWAVES 7
#define MT 2                    // M-tiles per wave
#define BLOCK (NWAVES * 64)     // 448 threads
#define CD_STRIDE 168           // bf16 elems per batch row (336 B = 21*16, b128-aligned)

typedef short bf16x8 __attribute__((ext_vector_type(8)));
typedef float f32x4  __attribute__((ext_vector_type(4)));

__device__ __constant__ int LM_IDX[NUM_LM] = {
    27440, 27208, 27608, 27816, 35472, 34766, 34312, 34022, 33838, 33654,
    33375, 32939, 32244, 16264, 16467, 16888, 16644, 31716, 31056, 30662,
    30454, 30288, 29549, 29382, 29177, 28787, 28111,  8161,  8177,  8187,
     8192,  9883,  9163,  8204,  7243,  6515, 14066, 12383, 11353, 10455,
    11492, 12653,  5828,  4920,  3886,  2215,  3640,  4801, 10795, 10395,
     8935,  8215,  7495,  6025,  5522,  6915,  7636,  8236,  8836,  9555,
    10537,  9064,  8223,  7384,  5909,  7629,  8229,  8829
};

// two f32 -> packed bf16x2 (RNE) -> v_cvt_pk_bf16_f32
__device__ __forceinline__ unsigned pk2(float x, float y) {
    __hip_bfloat162 h = __float22bfloat162_rn(float2{x, y});
    union { __hip_bfloat162 h; unsigned u; } c; c.h = h; return c.u;
}

__global__ __launch_bounds__(BLOCK) void fused_geo_loss(
        const float* __restrict__ alpha,
        const float* __restrict__ delta,
        const float* __restrict__ ref_alpha,
        const float* __restrict__ delta_pred,
        const float* __restrict__ id_base,
        const float* __restrict__ exp_base,
        float* __restrict__ out) {
    __shared__ __align__(16) unsigned short cdT[64 * CD_STRIDE];
    __shared__ float red[NWAVES];

    const int tid = threadIdx.x;
    const int w   = tid >> 6;      // wave: owns M-tiles 2w, 2w+1
    const int l   = tid & 63;      // lane
    const int mh  = l & 15;        // row-hat within tile (A) / col-hat (B)
    const int g   = l >> 4;        // k-group

    // ---- A-operand gather (global -> VGPR), issued first ----
    float4 af[MT][5][2];
    #pragma unroll
    for (int u = 0; u < MT; ++u) {
        const int  m     = 32 * w + 16 * u + mh;    // 0..223
        const bool valid = m < NROWS;
        const int  lmi   = valid ? (m / 3) : 0;
        const int  cc    = m - 3 * (m / 3);
        const long long vrow = 3LL * LM_IDX[lmi] + cc;
        const float* __restrict__ idp = id_base  + vrow * K_ID;
        const float* __restrict__ exq = exp_base + vrow * K_EXP;
        #pragma unroll
        for (int s = 0; s < 5; ++s) {
            const int k0 = 32 * s + g * 8;   // lane's 8-wide k-chunk, no straddle
            if (valid && k0 < K_ID) {
                af[u][s][0] = *(const float4*)(idp + k0);
                af[u][s][1] = *(const float4*)(idp + k0 + 4);
            } else if (valid && k0 < K_ID + K_EXP) {
                af[u][s][0] = *(const float4*)(exq + (k0 - K_ID));
                af[u][s][1] = *(const float4*)(exq + (k0 - K_ID) + 4);
            } else {
                af[u][s][0] = float4{0.f, 0.f, 0.f, 0.f};
                af[u][s][1] = float4{0.f, 0.f, 0.f, 0.f};
            }
        }
    }

    // ---- stage coeff diffs transposed into LDS as bf16: cdT[b][k] ----
    // 8 elements per iteration -> one ds_write_b128 each.
    for (int i = tid; i < (64 * K_ID) / 8; i += BLOCK) {        // 640 iters
        const int b = i / 10, k = 8 * (i - 10 * b);
        const float* ap = alpha     + b * K_ID + k;
        const float* rp = ref_alpha + b * K_ID + k;
        float4 a0 = *(const float4*)ap,       a1 = *(const float4*)(ap + 4);
        float4 r0 = *(const float4*)rp,       r1 = *(const float4*)(rp + 4);
        uint4 q;
        q.x = pk2(a0.x - r0.x, a0.y - r0.y);
        q.y = pk2(a0.z - r0.z, a0.w - r0.w);
        q.z = pk2(a1.x - r1.x, a1.y - r1.y);
        q.w = pk2(a1.z - r1.z, a1.w - r1.w);
        *(uint4*)&cdT[b * CD_STRIDE + k] = q;
    }
    for (int i = tid; i < (64 * K_EXP) / 8; i += BLOCK) {       // 512 iters
        const int b = i >> 3, k = 8 * (i & 7);
        const float* dp = delta      + b * K_EXP + k;
        const float* qp = delta_pred + b * K_EXP + k;
        float4 d0 = *(const float4*)dp,       d1 = *(const float4*)(dp + 4);
        float4 e0 = *(const float4*)qp,       e1 = *(const float4*)(qp + 4);
        uint4 q;
        q.x = pk2(d0.x - e0.x, d0.y - e0.y);
        q.y = pk2(d0.z - e0.z, d0.w - e0.w);
        q.z = pk2(d1.x - e1.x, d1.y - e1.y);
        q.w = pk2(d1.z - e1.z, d1.w - e1.w);
        *(uint4*)&cdT[b * CD_STRIDE + K_ID + k] = q;
    }
    for (int i = tid; i < 64 * 2; i += BLOCK) {                 // zero k=144..159
        const int b = i >> 1, k = 144 + 8 * (i & 1);
        *(uint4*)&cdT[b * CD_STRIDE + k] = uint4{0u, 0u, 0u, 0u};
    }

    // convert A fragments to bf16 (packed) while staging loads drain
    bf16x8 a[MT][5];
    #pragma unroll
    for (int u = 0; u < MT; ++u)
        #pragma unroll
        for (int s = 0; s < 5; ++s) {
            const float* fp = (const float*)&af[u][s][0];
            union { bf16x8 v; unsigned q[4]; } cv;
            #pragma unroll
            for (int j = 0; j < 4; ++j)
                cv.q[j] = pk2(fp[2 * j], fp[2 * j + 1]);
            a[u][s] = cv.v;
        }

    __syncthreads();

    // ---- MFMA: 5 k-steps x 4 N-tiles, B read once, reused for both M ----
    f32x4 acc[MT][4];
    const f32x4 z4 = {0.f, 0.f, 0.f, 0.f};
    #pragma unroll
    for (int u = 0; u < MT; ++u)
        #pragma unroll
        for (int t = 0; t < 4; ++t) acc[u][t] = z4;

    #pragma unroll
    for (int s = 0; s < 5; ++s) {
        bf16x8 bfrag[4];
        #pragma unroll
        for (int t = 0; t < 4; ++t)
            bfrag[t] = *(const bf16x8*)&cdT[(16 * t + mh) * CD_STRIDE + 32 * s + g * 8];
        #pragma unroll
        for (int u = 0; u < MT; ++u)
            #pragma unroll
            for (int t = 0; t < 4; ++t)
                acc[u][t] = __builtin_amdgcn_mfma_f32_16x16x32_bf16(
                    a[u][s], bfrag[t], acc[u][t], 0, 0, 0);
    }

    // ---- weighted square-sum; D layout: col=lane&15, row=(lane>>4)*4+reg ----
    float v = 0.f;
    #pragma unroll
    for (int u = 0; u < MT; ++u) {
        #pragma unroll
        for (int q = 0; q < 4; ++q) {
            const int row = 32 * w + 16 * u + 4 * g + q;
            float wq = 0.f;
            if (row < NROWS) {
                const int li = row / 3;
                wq = ((li >= 17 && li < 27) || li >= 36) ? 50.f : 1.f;
            }
            float sq = 0.f;
            #pragma unroll
            for (int t = 0; t < 4; ++t) sq += acc[u][t][q] * acc[u][t][q];
            v += wq * sq;
        }
    }
    #pragma unroll
    for (int off = 32; off; off >>= 1) v += __shfl_down(v, off, 64);
    if (l == 0) red[w] = v;
    __syncthreads();
    if (tid == 0) {
        float tot = 0.f;
        #pragma unroll
        for (int i = 0; i < NWAVES; ++i) tot += red[i];
        out[0] = tot * (1.0f / 68.0f);
    }
}

extern "C" void kernel_launch(void* const* d_in, const int* in_sizes, int n_in,
                              void* d_out, int out_size, void* d_ws, size_t ws_size,
                              hipStream_t stream) {
    const float* alpha      = (const float*)d_in[0];
    const float* delta      = (const float*)d_in[1];
    const float* ref_alpha  = (const float*)d_in[2];
    const float* delta_pred = (const float*)d_in[3];
    const float* id_base    = (const float*)d_in[4];
    const float* exp_base   = (const float*)d_in[5];
    float* out = (float*)d_out;

    fused_geo_loss<<<dim3(1), dim3(BLOCK), 0, stream>>>(
        alpha, delta, ref_alpha, delta_pred, id_base, exp_base, out);
}